// Round 15
// baseline (6708.027 us; speedup 1.0000x reference)
//
#include <hip/hip_runtime.h>

#define UNITS   2048
#define IN_DIM  128
#define T_STEPS 4096
#define NBLK    64
#define TPB     512
#define BROWS   32    // rows per block

typedef unsigned int u32;
typedef u32 u32x4 __attribute__((ext_vector_type(4)));
typedef u32 u32x2v __attribute__((ext_vector_type(2)));
typedef short short8 __attribute__((ext_vector_type(8)));
typedef __bf16 bf16x8 __attribute__((ext_vector_type(8)));
typedef float f32x4 __attribute__((ext_vector_type(4)));

// Zero comm words each call: tag 0 never matches (first polled tag is 1).
__global__ void esn_init(u32* __restrict__ buf) {
    int i = blockIdx.x * blockDim.x + threadIdx.x;
    if (i < 2 * UNITS) buf[i] = 0u;
}

__device__ __forceinline__ unsigned short f2bf(float f) {   // RNE float->bf16 bits
    u32 x = __float_as_uint(f);
    return (unsigned short)((x + 0x7FFFu + ((x >> 16) & 1u)) >> 16);
}

__global__ void __launch_bounds__(TPB, 2) esn_step(
    const float* __restrict__ inp,   // [4096][128]
    const float* __restrict__ s0,    // [2048]
    const float* __restrict__ W,     // [2048][2048] row-major
    const float* __restrict__ Win,   // [2048][128]
    float* __restrict__ out,         // [4096*2048 + 2048]
    u32* __restrict__ buf)           // [2][2048] packed (tag16|bf16) words
{
    const int b    = blockIdx.x;
    const int tid  = threadIdx.x;
    const int lane = tid & 63;
    const int wv   = tid >> 6;       // wave 0..7, all symmetric
    const int h8   = (lane >> 4) * 8;
    const int colr = lane & 15;

    __shared__ unsigned short sB[UNITS];     // bf16 state; [256w,256w+256) PRIVATE to wave w
    __shared__ float red[2][8][2][16];       // per-wave C partials
    __shared__ float s_state[BROWS];         // fp32 running state (own rows)
    __shared__ u32 cnt_mm[2];                // compute-done counters

    // ---- static A fragments: wave w covers K-slice [256w,256w+256), all 32 rows ----
    const int rbase = b * BROWS;
    bf16x8 a0[8], a1[8];
    #pragma unroll
    for (int tt = 0; tt < 8; ++tt) {
        const int kb = wv * 256 + tt * 32 + h8;
        short8 t0, t1;
        #pragma unroll
        for (int j = 0; j < 8; ++j) {
            t0[j] = (short)f2bf(W[(size_t)(rbase + colr) * UNITS + kb + j]);
            t1[j] = (short)f2bf(W[(size_t)(rbase + 16 + colr) * UNITS + kb + j]);
        }
        a0[tt] = *(bf16x8*)&t0;
        a1[tt] = *(bf16x8*)&t1;
    }
    bf16x8 ain0 = {}, ain1 = {};             // input A tiles (waves 0-3 only)
    const bool hasIn = (wv < 4);
    if (hasIn) {
        const int kb = wv * 32 + h8;
        short8 t0, t1;
        #pragma unroll
        for (int j = 0; j < 8; ++j) {
            t0[j] = (short)f2bf(Win[(size_t)(rbase + colr) * IN_DIM + kb + j]);
            t1[j] = (short)f2bf(Win[(size_t)(rbase + 16 + colr) * IN_DIM + kb + j]);
        }
        ain0 = *(bf16x8*)&t0;
        ain1 = *(bf16x8*)&t1;
    }

    // ---- pre-loop: deposit bf16(s_0) into own slice, init state/counters ----
    {
        float4 v = *(const float4*)(s0 + tid * 4);
        u32x2v pk;
        pk[0] = (u32)f2bf(v.x) | ((u32)f2bf(v.y) << 16);
        pk[1] = (u32)f2bf(v.z) | ((u32)f2bf(v.w) << 16);
        *(u32x2v*)&sB[tid * 4] = pk;
    }
    if (tid < BROWS) s_state[tid] = s0[rbase + tid];
    if (tid == 0) { cnt_mm[0] = 0u; cnt_mm[1] = 0u; }
    __syncthreads();   // one-time only

    for (int t = 0; t < T_STEPS; ++t) {
        const int par   = t & 1;
        const u32 epoch = (u32)(t >> 1) + 1u;
        const u32 tag   = (u32)t;
        const u32* pp   = buf + par * UNITS + tid * 4;

        // ---- input loads + input MFMAs first (independent of state) ----
        f32x4 c0a = {0.f,0.f,0.f,0.f}, c0b = {0.f,0.f,0.f,0.f};
        f32x4 c1a = {0.f,0.f,0.f,0.f}, c1b = {0.f,0.f,0.f,0.f};
        if (hasIn) {
            const float* ip = inp + (size_t)t * IN_DIM + wv * 32 + h8;
            float4 iA = *(const float4*)ip;
            float4 iB = *(const float4*)(ip + 4);
            short8 si;
            si[0] = (short)f2bf(iA.x); si[1] = (short)f2bf(iA.y);
            si[2] = (short)f2bf(iA.z); si[3] = (short)f2bf(iA.w);
            si[4] = (short)f2bf(iB.x); si[5] = (short)f2bf(iB.y);
            si[6] = (short)f2bf(iB.z); si[7] = (short)f2bf(iB.w);
            bf16x8 bin = *(bf16x8*)&si;
            c0b = __builtin_amdgcn_mfma_f32_16x16x32_bf16(ain0, bin, c0b, 0, 0, 0);
            c1b = __builtin_amdgcn_mfma_f32_16x16x32_bf16(ain1, bin, c1b, 0, 0, 0);
        }

        // ---- spin: counted depth-2 probe pipeline (sampling period ~RTT/2) ----
        if (t > 0) {
            u32x4 PA, PB, R;
            asm volatile("s_waitcnt vmcnt(0)" ::: "memory");   // exact counts from here
            asm volatile("global_load_dwordx4 %0, %1, off sc0 sc1"
                         : "=v"(PA) : "v"(pp) : "memory");
            asm volatile("global_load_dwordx4 %0, %1, off sc0 sc1"
                         : "=v"(PB) : "v"(pp) : "memory");
            while (true) {
                asm volatile("s_waitcnt vmcnt(1)" : "+v"(PA) :: "memory");  // PA done
                bool ok = ((PA[0] >> 16) == tag) & ((PA[1] >> 16) == tag)
                        & ((PA[2] >> 16) == tag) & ((PA[3] >> 16) == tag);
                if (ok) { R = PA; break; }
                asm volatile("global_load_dwordx4 %0, %1, off sc0 sc1"
                             : "=v"(PA) : "v"(pp) : "memory");
                asm volatile("s_waitcnt vmcnt(1)" : "+v"(PB) :: "memory");  // PB done
                ok = ((PB[0] >> 16) == tag) & ((PB[1] >> 16) == tag)
                   & ((PB[2] >> 16) == tag) & ((PB[3] >> 16) == tag);
                if (ok) { R = PB; break; }
                asm volatile("global_load_dwordx4 %0, %1, off sc0 sc1"
                             : "=v"(PB) : "v"(pp) : "memory");
            }
            asm volatile("s_waitcnt vmcnt(0)" ::: "memory");   // drain loser probe
            u32x2v pk;
            pk[0] = (R[0] & 0xFFFFu) | (R[1] << 16);
            pk[1] = (R[2] & 0xFFFFu) | (R[3] << 16);
            *(u32x2v*)&sB[tid * 4] = pk;     // same-wave write -> same-wave read
        }

        // ---- 32 state MFMAs in two independent chains per row-tile ----
        #pragma unroll
        for (int tt = 0; tt < 8; ++tt) {
            bf16x8 bb = *(const bf16x8*)&sB[wv * 256 + tt * 32 + h8];
            if (tt & 1) {
                c0b = __builtin_amdgcn_mfma_f32_16x16x32_bf16(a0[tt], bb, c0b, 0, 0, 0);
                c1b = __builtin_amdgcn_mfma_f32_16x16x32_bf16(a1[tt], bb, c1b, 0, 0, 0);
            } else {
                c0a = __builtin_amdgcn_mfma_f32_16x16x32_bf16(a0[tt], bb, c0a, 0, 0, 0);
                c1a = __builtin_amdgcn_mfma_f32_16x16x32_bf16(a1[tt], bb, c1a, 0, 0, 0);
            }
        }
        f32x4 acc0 = c0a + c0b, acc1 = c1a + c1b;

        // ---- C partials: col-0 lanes carry all rows (B replicated across cols) ----
        if (colr == 0) {
            *(f32x4*)&red[par][wv][0][(lane >> 4) * 4] = acc0;
            *(f32x4*)&red[par][wv][1][(lane >> 4) * 4] = acc1;
        }
        u32 rtn = 0;
        if (lane == 0)
            rtn = __hip_atomic_fetch_add(&cnt_mm[par], 1u, __ATOMIC_ACQ_REL,
                                         __HIP_MEMORY_SCOPE_WORKGROUP);
        rtn = __shfl(rtn, 0);

        // ---- last-finishing wave finalizes + publishes immediately ----
        if (rtn == 8u * epoch - 1u && lane < BROWS) {
            const int rt = lane >> 4, rr = lane & 15;
            float pre = 0.f;
            #pragma unroll
            for (int w8 = 0; w8 < 8; ++w8) pre += red[par][w8][rt][rr];
            float e  = __expf(2.0f * pre);
            float th = 1.0f - 2.0f / (e + 1.0f);
            float sn = 0.9f * s_state[lane] + 0.1f * th;
            s_state[lane] = sn;
            const int j = rbase + lane;
            if (t < T_STEPS - 1) {
                u32 word = ((u32)(t + 1) << 16) | (u32)f2bf(sn);
                u32* ps = buf + ((t + 1) & 1) * UNITS + j;   // contiguous 128B/block
                asm volatile("global_store_dword %0, %1, off sc0 sc1"
                             :: "v"(ps), "v"(word) : "memory");
            }
            out[(size_t)t * UNITS + j] = sn;
            if (t == T_STEPS - 1) out[(size_t)T_STEPS * UNITS + j] = sn;
        }
    }
}

extern "C" void kernel_launch(void* const* d_in, const int* in_sizes, int n_in,
                              void* d_out, int out_size, void* d_ws, size_t ws_size,
                              hipStream_t stream) {
    const float* inp = (const float*)d_in[0];   // input_sequence [4096,128]
    const float* s0  = (const float*)d_in[1];   // initial_state  [1,2048]
    const float* W   = (const float*)d_in[2];   // W   [2048,2048]
    const float* Win = (const float*)d_in[3];   // Win [2048,128]
    float* out = (float*)d_out;
    u32* buf = (u32*)d_ws;                      // 2*2048*4 = 16 KiB scratch

    esn_init<<<dim3(16), dim3(256), 0, stream>>>(buf);

    void* args[6];
    args[0] = (void*)&inp; args[1] = (void*)&s0;  args[2] = (void*)&W;
    args[3] = (void*)&Win; args[4] = (void*)&out; args[5] = (void*)&buf;
    hipLaunchCooperativeKernel((void*)esn_step, dim3(NBLK), dim3(TPB), args, 0, stream);
}

// Round 16
// 5954.431 us; speedup vs baseline: 1.1266x; 1.1266x over previous
//
#include <hip/hip_runtime.h>

#define UNITS   2048
#define IN_DIM  128
#define T_STEPS 4096
#define NBLK    64
#define TPB     512
#define BROWS   32    // rows per block

typedef unsigned int u32;
typedef u32 u32x4 __attribute__((ext_vector_type(4)));
typedef u32 u32x2v __attribute__((ext_vector_type(2)));
typedef short short8 __attribute__((ext_vector_type(8)));
typedef __bf16 bf16x8 __attribute__((ext_vector_type(8)));
typedef float f32x4 __attribute__((ext_vector_type(4)));

// Zero comm words each call: tag 0 never matches (first polled tag is 1).
__global__ void esn_init(u32* __restrict__ buf) {
    int i = blockIdx.x * blockDim.x + threadIdx.x;
    if (i < 2 * UNITS) buf[i] = 0u;
}

__device__ __forceinline__ unsigned short f2bf(float f) {   // RNE float->bf16 bits
    u32 x = __float_as_uint(f);
    return (unsigned short)((x + 0x7FFFu + ((x >> 16) & 1u)) >> 16);
}

__global__ void __launch_bounds__(TPB, 2) esn_step(
    const float* __restrict__ inp,   // [4096][128]
    const float* __restrict__ s0,    // [2048]
    const float* __restrict__ W,     // [2048][2048] row-major
    const float* __restrict__ Win,   // [2048][128]
    float* __restrict__ out,         // [4096*2048 + 2048]
    u32* __restrict__ buf)           // [2][2048] packed (tag16|bf16) words
{
    const int b    = blockIdx.x;
    const int tid  = threadIdx.x;
    const int lane = tid & 63;
    const int wv   = tid >> 3 >> 3;  // == tid >> 6, wave 0..7 (all symmetric)
    const int h8   = (lane >> 4) * 8;
    const int colr = lane & 15;

    __shared__ unsigned short sB[UNITS];     // bf16 state; slice [256w,256w+256) PRIVATE to wave w
    __shared__ float red[2][8][2][16];       // per-wave C partials (parity, wave, row-tile, row)
    __shared__ float s_state[BROWS];         // fp32 running state (own rows)
    __shared__ u32 cnt_mm[2];                // compute-done counters

    // ---- static A fragments: wave w covers K-slice [256w, 256w+256), all 32 rows ----
    const int rbase = b * BROWS;
    bf16x8 a0[8], a1[8];                     // row-tile 0 (rows 0-15), row-tile 1 (16-31)
    #pragma unroll
    for (int tt = 0; tt < 8; ++tt) {
        const int kb = wv * 256 + tt * 32 + h8;
        short8 t0, t1;
        #pragma unroll
        for (int j = 0; j < 8; ++j) {
            t0[j] = (short)f2bf(W[(size_t)(rbase + colr) * UNITS + kb + j]);
            t1[j] = (short)f2bf(W[(size_t)(rbase + 16 + colr) * UNITS + kb + j]);
        }
        a0[tt] = *(bf16x8*)&t0;
        a1[tt] = *(bf16x8*)&t1;
    }
    bf16x8 ain0 = {}, ain1 = {};             // input A tiles (waves 0-3 only)
    const bool hasIn = (wv < 4);
    if (hasIn) {
        const int kb = wv * 32 + h8;
        short8 t0, t1;
        #pragma unroll
        for (int j = 0; j < 8; ++j) {
            t0[j] = (short)f2bf(Win[(size_t)(rbase + colr) * IN_DIM + kb + j]);
            t1[j] = (short)f2bf(Win[(size_t)(rbase + 16 + colr) * IN_DIM + kb + j]);
        }
        ain0 = *(bf16x8*)&t0;
        ain1 = *(bf16x8*)&t1;
    }

    // ---- pre-loop: deposit bf16(s_0) into own slice, init state/counters ----
    {
        float4 v = *(const float4*)(s0 + tid * 4);
        u32x2v pk;
        pk[0] = (u32)f2bf(v.x) | ((u32)f2bf(v.y) << 16);
        pk[1] = (u32)f2bf(v.z) | ((u32)f2bf(v.w) << 16);
        *(u32x2v*)&sB[tid * 4] = pk;
    }
    if (tid < BROWS) s_state[tid] = s0[rbase + tid];
    if (tid == 0) { cnt_mm[0] = 0u; cnt_mm[1] = 0u; }
    __syncthreads();   // one-time only

    for (int t = 0; t < T_STEPS; ++t) {
        const int par   = t & 1;
        const u32 epoch = (u32)(t >> 1) + 1u;
        const u32 tag   = (u32)t;

        // ---- issue own poll first (16B covers this lane's 4 units) ----
        const u32* pp = buf + par * UNITS + tid * 4;
        u32x4 A;
        if (t > 0)
            asm volatile("global_load_dwordx4 %0, %1, off sc0 sc1"
                         : "=v"(A) : "v"(pp) : "memory");

        // ---- input loads overlap the first poll RTT ----
        float4 iA, iB;
        if (hasIn) {
            const float* ip = inp + (size_t)t * IN_DIM + wv * 32 + h8;
            iA = *(const float4*)ip;
            iB = *(const float4*)(ip + 4);
        }

        // ---- spin: detect own 4 tags, redeposit into wave-private LDS slice ----
        if (t > 0) {
            while (true) {
                asm volatile("s_waitcnt vmcnt(0)" : "+v"(A) :: "memory");
                bool ok = ((A[0] >> 16) == tag) & ((A[1] >> 16) == tag)
                        & ((A[2] >> 16) == tag) & ((A[3] >> 16) == tag);
                if (ok) break;
                asm volatile("global_load_dwordx4 %0, %1, off sc0 sc1"
                             : "=v"(A) : "v"(pp) : "memory");
            }
            u32x2v pk;
            pk[0] = (A[0] & 0xFFFFu) | (A[1] << 16);
            pk[1] = (A[2] & 0xFFFFu) | (A[3] << 16);
            *(u32x2v*)&sB[tid * 4] = pk;     // same-wave write -> same-wave read: no barrier
        }

        // ---- MFMAs: 4 independent chains; input tiles first ----
        f32x4 c0a = {0.f,0.f,0.f,0.f}, c0b = {0.f,0.f,0.f,0.f};
        f32x4 c1a = {0.f,0.f,0.f,0.f}, c1b = {0.f,0.f,0.f,0.f};
        if (hasIn) {
            short8 si;
            si[0] = (short)f2bf(iA.x); si[1] = (short)f2bf(iA.y);
            si[2] = (short)f2bf(iA.z); si[3] = (short)f2bf(iA.w);
            si[4] = (short)f2bf(iB.x); si[5] = (short)f2bf(iB.y);
            si[6] = (short)f2bf(iB.z); si[7] = (short)f2bf(iB.w);
            bf16x8 bin = *(bf16x8*)&si;
            c0b = __builtin_amdgcn_mfma_f32_16x16x32_bf16(ain0, bin, c0b, 0, 0, 0);
            c1b = __builtin_amdgcn_mfma_f32_16x16x32_bf16(ain1, bin, c1b, 0, 0, 0);
        }
        #pragma unroll
        for (int tt = 0; tt < 8; ++tt) {
            bf16x8 bb = *(const bf16x8*)&sB[wv * 256 + tt * 32 + h8];
            if (tt & 1) {
                c0b = __builtin_amdgcn_mfma_f32_16x16x32_bf16(a0[tt], bb, c0b, 0, 0, 0);
                c1b = __builtin_amdgcn_mfma_f32_16x16x32_bf16(a1[tt], bb, c1b, 0, 0, 0);
            } else {
                c0a = __builtin_amdgcn_mfma_f32_16x16x32_bf16(a0[tt], bb, c0a, 0, 0, 0);
                c1a = __builtin_amdgcn_mfma_f32_16x16x32_bf16(a1[tt], bb, c1a, 0, 0, 0);
            }
        }
        f32x4 acc0 = c0a + c0b, acc1 = c1a + c1b;

        // ---- C partials: col-0 lanes carry all rows (B replicated across cols) ----
        if (colr == 0) {
            *(f32x4*)&red[par][wv][0][(lane >> 4) * 4] = acc0;
            *(f32x4*)&red[par][wv][1][(lane >> 4) * 4] = acc1;
        }
        u32 rtn = 0;
        if (lane == 0)
            rtn = __hip_atomic_fetch_add(&cnt_mm[par], 1u, __ATOMIC_ACQ_REL,
                                         __HIP_MEMORY_SCOPE_WORKGROUP);
        rtn = __shfl(rtn, 0);

        // ---- last-finishing wave finalizes + publishes immediately ----
        if (rtn == 8u * epoch - 1u && lane < BROWS) {
            const int rt = lane >> 4, rr = lane & 15;
            float pre = 0.f;
            #pragma unroll
            for (int w8 = 0; w8 < 8; ++w8) pre += red[par][w8][rt][rr];
            float e  = __expf(2.0f * pre);
            float th = 1.0f - 2.0f / (e + 1.0f);
            float sn = 0.9f * s_state[lane] + 0.1f * th;
            s_state[lane] = sn;
            const int j = rbase + lane;
            if (t < T_STEPS - 1) {
                u32 word = ((u32)(t + 1) << 16) | (u32)f2bf(sn);
                u32* ps = buf + ((t + 1) & 1) * UNITS + j;   // contiguous 128B/block
                asm volatile("global_store_dword %0, %1, off sc0 sc1"
                             :: "v"(ps), "v"(word) : "memory");
            }
            out[(size_t)t * UNITS + j] = sn;
            if (t == T_STEPS - 1) out[(size_t)T_STEPS * UNITS + j] = sn;
        }
    }
}

extern "C" void kernel_launch(void* const* d_in, const int* in_sizes, int n_in,
                              void* d_out, int out_size, void* d_ws, size_t ws_size,
                              hipStream_t stream) {
    const float* inp = (const float*)d_in[0];   // input_sequence [4096,128]
    const float* s0  = (const float*)d_in[1];   // initial_state  [1,2048]
    const float* W   = (const float*)d_in[2];   // W   [2048,2048]
    const float* Win = (const float*)d_in[3];   // Win [2048,128]
    float* out = (float*)d_out;
    u32* buf = (u32*)d_ws;                      // 2*2048*4 = 16 KiB scratch

    esn_init<<<dim3(16), dim3(256), 0, stream>>>(buf);

    void* args[6];
    args[0] = (void*)&inp; args[1] = (void*)&s0;  args[2] = (void*)&W;
    args[3] = (void*)&Win; args[4] = (void*)&out; args[5] = (void*)&buf;
    hipLaunchCooperativeKernel((void*)esn_step, dim3(NBLK), dim3(TPB), args, 0, stream);
}